// Round 16
// baseline (4047.960 us; speedup 1.0000x reference)
//
#include <hip/hip_runtime.h>

// Seq2Seq GRU + Bahdanau attention, fp32. B=32 S=64 T=48 E=512 H=1024 V=32000.
// R16 = R15 + transposed encproj ([B][col][S] via GEMM tmode=1 epilogue) and
// k_attn_fin at 256 blocks (8 parts/batch): xsum reads 64 contiguous floats
// per thread (16 pipelined f32x4 loads) instead of 64 stride-12KB scalars.

#define BB 32
#define SS 64
#define TT 48
#define TD 47
#define EE 512
#define HH 1024
#define GG 3072
#define VV 32000
#define SOS_IDX 1
#define MPAD 1536          // 1504 rows padded to 12*128

typedef float f32x4 __attribute__((ext_vector_type(4)));
typedef short bf16x8 __attribute__((ext_vector_type(8)));

static __device__ __forceinline__ float sigmoid_f(float x) {
    return 1.0f / (1.0f + __expf(-x));
}
static __device__ __forceinline__ float tanh_f(float x) {
    return 1.0f - 2.0f / (__expf(2.0f * x) + 1.0f);
}
static __device__ __forceinline__ unsigned short f2bf(float f) {
    unsigned u = __float_as_uint(f);
    u = u + 0x7fffu + ((u >> 16) & 1u);
    return (unsigned short)(u >> 16);
}

__global__ void k_dec_idx(const int* __restrict__ tgt, int* __restrict__ idx) {
    int m = blockIdx.x * 256 + threadIdx.x;
    if (m < TD * BB) {
        int t = m >> 5, b = m & 31;
        idx[m] = (t == 0) ? SOS_IDX : tgt[b * TT + t];
    }
}

// ---------------- fp32 128x128 GEMM ----------------
// tmode==1 (encproj): output written transposed as C[b][col][s], s=m&63.
__global__ __launch_bounds__(256) void k_gemm128(
    const float* __restrict__ A, const float* __restrict__ Wt,
    const float* __restrict__ bias, float* __restrict__ C,
    const int* __restrict__ rowidx,
    int M, int N, int K, int lda, int ldw, int ldc, int tmode)
{
    __shared__ __align__(16) float As[16][128];
    __shared__ __align__(16) float Bs[16][128];
    const int tid = threadIdx.x;
    const int tm = tid >> 4, tn = tid & 15;
    const int row0 = blockIdx.y * 128;
    const int col0 = blockIdx.x * 128;
    const int lr = tid >> 1;
    const int lq = tid & 1;

    long arow_off = -1;
    {
        int arow = row0 + lr;
        if (arow < M) {
            int r = rowidx ? rowidx[arow] : arow;
            arow_off = (long)r * lda;
        }
    }
    const long wrow_off = (long)(col0 + lr) * ldw;

    float acc[8][8];
#pragma unroll
    for (int i = 0; i < 8; ++i)
#pragma unroll
        for (int j = 0; j < 8; ++j) acc[i][j] = 0.f;

    for (int k0 = 0; k0 < K; k0 += 16) {
        f32x4 av0 = {0.f,0.f,0.f,0.f}, av1 = {0.f,0.f,0.f,0.f};
        if (arow_off >= 0) {
            av0 = *(const f32x4*)(A + arow_off + k0 + lq * 8);
            av1 = *(const f32x4*)(A + arow_off + k0 + lq * 8 + 4);
        }
        f32x4 wv0 = *(const f32x4*)(Wt + wrow_off + k0 + lq * 8);
        f32x4 wv1 = *(const f32x4*)(Wt + wrow_off + k0 + lq * 8 + 4);
        __syncthreads();
#pragma unroll
        for (int i = 0; i < 4; ++i) {
            As[lq * 8 + i][lr] = av0[i];
            As[lq * 8 + 4 + i][lr] = av1[i];
            Bs[lq * 8 + i][lr] = wv0[i];
            Bs[lq * 8 + 4 + i][lr] = wv1[i];
        }
        __syncthreads();
#pragma unroll
        for (int kk = 0; kk < 16; ++kk) {
            f32x4 a0 = *(const f32x4*)&As[kk][tm * 4];
            f32x4 a1 = *(const f32x4*)&As[kk][64 + tm * 4];
            f32x4 b0 = *(const f32x4*)&Bs[kk][tn * 4];
            f32x4 b1 = *(const f32x4*)&Bs[kk][64 + tn * 4];
            float a[8], b[8];
#pragma unroll
            for (int i = 0; i < 4; ++i) {
                a[i] = a0[i]; a[4 + i] = a1[i];
                b[i] = b0[i]; b[4 + i] = b1[i];
            }
#pragma unroll
            for (int i = 0; i < 8; ++i)
#pragma unroll
                for (int j = 0; j < 8; ++j) acc[i][j] += a[i] * b[j];
        }
    }

    f32x4 bv0 = {0.f,0.f,0.f,0.f}, bv1 = {0.f,0.f,0.f,0.f};
    if (bias) {
        bv0 = *(const f32x4*)(bias + col0 + tn * 4);
        bv1 = *(const f32x4*)(bias + col0 + 64 + tn * 4);
    }
    if (tmode == 1) {
        // transposed epilogue: C[(b*GG + col)*64 + s]
#pragma unroll
        for (int i = 0; i < 8; ++i) {
            int m = row0 + ((i < 4) ? (tm * 4 + i) : (64 + tm * 4 + i - 4));
            if (m >= M) continue;
            int b = m >> 6, s = m & 63;
            float* base = C + ((size_t)b * GG) * 64 + s;
#pragma unroll
            for (int j = 0; j < 4; ++j) {
                base[(size_t)(col0 + tn * 4 + j) * 64] = acc[i][j] + bv0[j];
                base[(size_t)(col0 + 64 + tn * 4 + j) * 64] = acc[i][4 + j] + bv1[j];
            }
        }
        return;
    }
#pragma unroll
    for (int i = 0; i < 8; ++i) {
        int m = row0 + ((i < 4) ? (tm * 4 + i) : (64 + tm * 4 + i - 4));
        if (m >= M) continue;
        f32x4 v0, v1;
#pragma unroll
        for (int j = 0; j < 4; ++j) {
            v0[j] = acc[i][j] + bv0[j];
            v1[j] = acc[i][4 + j] + bv1[j];
        }
        *(f32x4*)(C + (long)m * ldc + col0 + tn * 4) = v0;
        *(f32x4*)(C + (long)m * ldc + col0 + 64 + tn * 4) = v1;
    }
}

// ---------------- conversions for split-bf16 logits ----------------
__global__ __launch_bounds__(256) void k_cvtA(
    const float* __restrict__ A, unsigned short* __restrict__ Ah,
    unsigned short* __restrict__ Al)
{
    size_t i4 = ((size_t)blockIdx.x * 256 + threadIdx.x) * 4;
    int row = (int)(i4 >> 10);
    f32x4 v = {0.f, 0.f, 0.f, 0.f};
    if (row < TD * BB) v = *(const f32x4*)(A + i4);
    ushort4 h, l;
    float hf;
    h.x = f2bf(v.x); hf = __uint_as_float((unsigned)h.x << 16); l.x = f2bf(v.x - hf);
    h.y = f2bf(v.y); hf = __uint_as_float((unsigned)h.y << 16); l.y = f2bf(v.y - hf);
    h.z = f2bf(v.z); hf = __uint_as_float((unsigned)h.z << 16); l.z = f2bf(v.z - hf);
    h.w = f2bf(v.w); hf = __uint_as_float((unsigned)h.w << 16); l.w = f2bf(v.w - hf);
    *(ushort4*)(Ah + i4) = h;
    *(ushort4*)(Al + i4) = l;
}

__global__ __launch_bounds__(256) void k_cvtB(
    const float* __restrict__ Bsrc, unsigned short* __restrict__ Bh)
{
    size_t i4 = ((size_t)blockIdx.x * 256 + threadIdx.x) * 4;
    f32x4 v = *(const f32x4*)(Bsrc + i4);
    ushort4 h;
    h.x = f2bf(v.x); h.y = f2bf(v.y); h.z = f2bf(v.z); h.w = f2bf(v.w);
    *(ushort4*)(Bh + i4) = h;
}

// ---------------- split-bf16 MFMA logits GEMM (R15) ----------------
__global__ __launch_bounds__(256) void k_mfma_logits(
    const unsigned short* __restrict__ Ah,
    const unsigned short* __restrict__ Bh,
    const float* __restrict__ bo, float* __restrict__ C)
{
    __shared__ __align__(16) unsigned short As0[128 * 64];
    __shared__ __align__(16) unsigned short As1[128 * 64];
    __shared__ __align__(16) unsigned short Bs[128 * 64];
    const int tid = threadIdx.x;
    const int m0 = blockIdx.x * 128;
    const int n0 = blockIdx.y * 128;
    const int r = tid >> 1, half = tid & 1;
    const int lane = tid & 63, wid = tid >> 6;
    const int wm = wid >> 1, wn = wid & 1;

    f32x4 acc[4][4];
#pragma unroll
    for (int i = 0; i < 4; ++i)
#pragma unroll
        for (int j = 0; j < 4; ++j) acc[i][j] = (f32x4){0.f, 0.f, 0.f, 0.f};

    char* As0B = (char*)As0;
    char* As1B = (char*)As1;
    char* BsB  = (char*)Bs;
    const int lwb = r * 128 + half * 64;
    const int swz = (r & 7) << 4;

    for (int kt = 0; kt < 16; ++kt) {
        const int kb = kt * 64;
        const unsigned short* Ap0 = Ah + (size_t)(m0 + r) * 1024 + kb + half * 32;
        const unsigned short* Ap1 = Ap0 + (size_t)MPAD * 1024;
        const unsigned short* Bp  = Bh + (size_t)(n0 + r) * 1024 + kb + half * 32;
        f32x4 a0 = *(const f32x4*)(Ap0 + 0);
        f32x4 a1 = *(const f32x4*)(Ap0 + 8);
        f32x4 a2 = *(const f32x4*)(Ap0 + 16);
        f32x4 a3 = *(const f32x4*)(Ap0 + 24);
        f32x4 c0 = *(const f32x4*)(Ap1 + 0);
        f32x4 c1 = *(const f32x4*)(Ap1 + 8);
        f32x4 c2 = *(const f32x4*)(Ap1 + 16);
        f32x4 c3 = *(const f32x4*)(Ap1 + 24);
        f32x4 b0 = *(const f32x4*)(Bp + 0);
        f32x4 b1 = *(const f32x4*)(Bp + 8);
        f32x4 b2 = *(const f32x4*)(Bp + 16);
        f32x4 b3 = *(const f32x4*)(Bp + 24);
        __syncthreads();
        *(f32x4*)(As0B + ((lwb + 0)  ^ swz)) = a0;
        *(f32x4*)(As0B + ((lwb + 16) ^ swz)) = a1;
        *(f32x4*)(As0B + ((lwb + 32) ^ swz)) = a2;
        *(f32x4*)(As0B + ((lwb + 48) ^ swz)) = a3;
        *(f32x4*)(As1B + ((lwb + 0)  ^ swz)) = c0;
        *(f32x4*)(As1B + ((lwb + 16) ^ swz)) = c1;
        *(f32x4*)(As1B + ((lwb + 32) ^ swz)) = c2;
        *(f32x4*)(As1B + ((lwb + 48) ^ swz)) = c3;
        *(f32x4*)(BsB  + ((lwb + 0)  ^ swz)) = b0;
        *(f32x4*)(BsB  + ((lwb + 16) ^ swz)) = b1;
        *(f32x4*)(BsB  + ((lwb + 32) ^ swz)) = b2;
        *(f32x4*)(BsB  + ((lwb + 48) ^ swz)) = b3;
        __syncthreads();
#pragma unroll
        for (int ks = 0; ks < 2; ++ks) {
            bf16x8 bf[4], af[4], ag[4];
#pragma unroll
            for (int u = 0; u < 4; ++u) {
                int nl = wn * 64 + u * 16 + (lane & 15);
                int byteB = nl * 128 + ks * 64 + ((lane >> 4) << 4);
                bf[u] = *(const bf16x8*)(BsB + (byteB ^ ((nl & 7) << 4)));
                int ml = wm * 64 + u * 16 + (lane & 15);
                int byteA = ml * 128 + ks * 64 + ((lane >> 4) << 4);
                af[u] = *(const bf16x8*)(As0B + (byteA ^ ((ml & 7) << 4)));
                ag[u] = *(const bf16x8*)(As1B + (byteA ^ ((ml & 7) << 4)));
            }
#pragma unroll
            for (int mi = 0; mi < 4; ++mi)
#pragma unroll
                for (int ni = 0; ni < 4; ++ni) {
                    acc[mi][ni] = __builtin_amdgcn_mfma_f32_16x16x32_bf16(
                        af[mi], bf[ni], acc[mi][ni], 0, 0, 0);
                    acc[mi][ni] = __builtin_amdgcn_mfma_f32_16x16x32_bf16(
                        ag[mi], bf[ni], acc[mi][ni], 0, 0, 0);
                }
        }
    }

    const int cl = lane & 15, rq = lane >> 4;
#pragma unroll
    for (int ni = 0; ni < 4; ++ni) {
        int col = n0 + wn * 64 + ni * 16 + cl;
        float bias = bo[col];
#pragma unroll
        for (int mi = 0; mi < 4; ++mi) {
#pragma unroll
            for (int j = 0; j < 4; ++j) {
                int m = m0 + wm * 64 + mi * 16 + rq * 4 + j;
                if (m < TD * BB) {
                    int orow = (m & 31) * TD + (m >> 5);
                    C[(size_t)orow * VV + col] = acc[mi][ni][j] + bias;
                }
            }
        }
    }
}

// ---------------- encoder step ----------------
__global__ __launch_bounds__(512, 2) void k_enc_step(
    const float* __restrict__ gi, const float* __restrict__ Whh,
    const float* __restrict__ bhh, float* __restrict__ enc_out, int s)
{
    __shared__ float red[12][16][32];
    __shared__ float sums[12][32];
    const int tid = threadIdx.x, bid = blockIdx.x;
    const int b = tid & 31, ks = tid >> 5;
    const int j0 = bid * 4;
    const int kc = ks * 64;

    float acc[12];
#pragma unroll
    for (int u = 0; u < 12; ++u) acc[u] = 0.f;
    if (s > 0) {
        f32x4 hreg[16];
        const float* hb = enc_out + ((size_t)b * SS + (s - 1)) * HH + kc;
#pragma unroll
        for (int i = 0; i < 16; ++i) hreg[i] = *(const f32x4*)(hb + (i << 2));
#pragma unroll
        for (int jj = 0; jj < 4; ++jj) {
            const float* pr = Whh + ((size_t)(j0 + jj) << 10) + kc;
            const float* pz = Whh + ((size_t)(HH + j0 + jj) << 10) + kc;
            const float* pn = Whh + ((size_t)(2 * HH + j0 + jj) << 10) + kc;
            float ar = 0.f, az = 0.f, an = 0.f;
#pragma unroll
            for (int i = 0; i < 16; ++i) {
                f32x4 h4 = hreg[i];
                f32x4 w;
                w = *(const f32x4*)(pr + (i << 2));
                ar += h4.x * w.x + h4.y * w.y + h4.z * w.z + h4.w * w.w;
                w = *(const f32x4*)(pz + (i << 2));
                az += h4.x * w.x + h4.y * w.y + h4.z * w.z + h4.w * w.w;
                w = *(const f32x4*)(pn + (i << 2));
                an += h4.x * w.x + h4.y * w.y + h4.z * w.z + h4.w * w.w;
            }
            acc[jj] = ar; acc[4 + jj] = az; acc[8 + jj] = an;
        }
    }
#pragma unroll
    for (int u = 0; u < 12; ++u) red[u][ks][b] = acc[u];
    __syncthreads();
    if (tid < 384) {
        int u = tid >> 5, fb = tid & 31;
        float x = 0.f;
#pragma unroll
        for (int q = 0; q < 16; ++q) x += red[u][q][fb];
        sums[u][fb] = x;
    }
    __syncthreads();
    if (tid < 32) {
        const f32x4 bh0 = *(const f32x4*)(bhh + j0);
        const f32x4 bh1 = *(const f32x4*)(bhh + HH + j0);
        const f32x4 bh2 = *(const f32x4*)(bhh + 2 * HH + j0);
        const float* gr = gi + (size_t)(tid * SS + s) * GG;
        f32x4 g0 = *(const f32x4*)(gr + j0);
        f32x4 g1 = *(const f32x4*)(gr + HH + j0);
        f32x4 g2 = *(const f32x4*)(gr + 2 * HH + j0);
        f32x4 hold = {0.f, 0.f, 0.f, 0.f};
        if (s > 0) hold = *(const f32x4*)(enc_out + ((size_t)tid * SS + (s - 1)) * HH + j0);
        f32x4 hn;
#pragma unroll
        for (int e = 0; e < 4; ++e) {
            float r = sigmoid_f(g0[e] + sums[e][tid] + bh0[e]);
            float z = sigmoid_f(g1[e] + sums[4 + e][tid] + bh1[e]);
            float n = tanh_f(g2[e] + r * (sums[8 + e][tid] + bh2[e]));
            hn[e] = (1.f - z) * n + z * hold[e];
        }
        *(f32x4*)(enc_out + ((size_t)tid * SS + s) * HH + j0) = hn;
    }
}

// ---------------- decoder K1: h-side dots + q ----------------
__global__ __launch_bounds__(512, 2) void k_hq(
    const float* __restrict__ hbase, long hstride,
    const float* __restrict__ Whh, const float* __restrict__ wq,
    const float* __restrict__ bq, float* __restrict__ qbuf,
    float* __restrict__ hsums)
{
    __shared__ float red[16][16][32];
    __shared__ float qsum[4][32];
    const int tid = threadIdx.x, bid = blockIdx.x;
    const int b = tid & 31, ks = tid >> 5;
    const int j0 = bid * 4;
    const int kc = ks * 64;

    f32x4 hreg[16];
    const float* hb = hbase + (size_t)b * hstride + kc;
#pragma unroll
    for (int i = 0; i < 16; ++i) hreg[i] = *(const f32x4*)(hb + (i << 2));
    float acc[16];
#pragma unroll
    for (int jj = 0; jj < 4; ++jj) {
        const float* pr = Whh + ((size_t)(j0 + jj) << 10) + kc;
        const float* pz = Whh + ((size_t)(HH + j0 + jj) << 10) + kc;
        const float* pn = Whh + ((size_t)(2 * HH + j0 + jj) << 10) + kc;
        const float* pq = wq + ((size_t)(j0 + jj) << 10) + kc;
        float ar = 0.f, az = 0.f, an = 0.f, aq = 0.f;
#pragma unroll
        for (int i = 0; i < 16; ++i) {
            f32x4 h4 = hreg[i];
            f32x4 w;
            w = *(const f32x4*)(pr + (i << 2));
            ar += h4.x * w.x + h4.y * w.y + h4.z * w.z + h4.w * w.w;
            w = *(const f32x4*)(pz + (i << 2));
            az += h4.x * w.x + h4.y * w.y + h4.z * w.z + h4.w * w.w;
            w = *(const f32x4*)(pn + (i << 2));
            an += h4.x * w.x + h4.y * w.y + h4.z * w.z + h4.w * w.w;
            w = *(const f32x4*)(pq + (i << 2));
            aq += h4.x * w.x + h4.y * w.y + h4.z * w.z + h4.w * w.w;
        }
        acc[jj] = ar; acc[4 + jj] = az; acc[8 + jj] = an; acc[12 + jj] = aq;
    }
#pragma unroll
    for (int u = 0; u < 16; ++u) red[u][ks][b] = acc[u];
    __syncthreads();
    {
        int u = tid >> 5, fb = tid & 31;
        float x = 0.f;
#pragma unroll
        for (int q = 0; q < 16; ++q) x += red[u][q][fb];
        if (u < 12) {
            int g = u >> 2, jj = u & 3;
            hsums[(size_t)g * BB * HH + (size_t)fb * HH + j0 + jj] = x;
        } else {
            qsum[u - 12][fb] = x;
        }
    }
    __syncthreads();
    if (tid < 32) {
        const f32x4 bq4 = *(const f32x4*)(bq + j0);
        f32x4 qv;
        qv.x = qsum[0][tid] + bq4.x;
        qv.y = qsum[1][tid] + bq4.y;
        qv.z = qsum[2][tid] + bq4.z;
        qv.w = qsum[3][tid] + bq4.w;
        *(f32x4*)(qbuf + (size_t)tid * HH + j0) = qv;
    }
}

// ---------------- decoder K2: attention + xsum + finalize ----------------
// 256 blocks: ab = bid&31, part = bid>>5 (0..7). All parts compute
// scores+softmax (redundant, cheap); part handles 384 encprojT cols
// (3 gates x 128 j) and finalizes j in [part*128, part*128+128).
__global__ __launch_bounds__(512, 2) void k_attn_fin(
    const float* __restrict__ qbuf, const float* __restrict__ keys,
    const float* __restrict__ wsv, const float* __restrict__ bsv,
    const int* __restrict__ src, const float* __restrict__ encprojT,
    const float* __restrict__ gi, const float* __restrict__ bhh,
    const float* __restrict__ hsums, const float* __restrict__ hbase,
    long hstride, float* __restrict__ h2all, float* __restrict__ attn_out,
    int t)
{
    __shared__ float qs[HH];
    __shared__ float wss[HH];
    __shared__ float sc[8][64];
    __shared__ float wl[64];
    __shared__ float xls[384];
    const int ab = blockIdx.x & 31, part = blockIdx.x >> 5;
    const int tid = threadIdx.x;
    if (tid < 256) {
        *(f32x4*)&qs[tid * 4] = *(const f32x4*)(qbuf + (size_t)ab * HH + tid * 4);
        *(f32x4*)&wss[tid * 4] = *(const f32x4*)(wsv + tid * 4);
    }
    __syncthreads();
    {
        const int s4 = tid >> 3, kq = tid & 7;
        const float* kr = keys + (size_t)(ab * SS + s4) * HH + kq * 128;
        float a = 0.f;
        for (int i = 0; i < 32; ++i) {
            f32x4 kv = *(const f32x4*)(kr + (i << 2));
            int k = kq * 128 + (i << 2);
            a += tanh_f(qs[k] + kv.x) * wss[k]
               + tanh_f(qs[k + 1] + kv.y) * wss[k + 1]
               + tanh_f(qs[k + 2] + kv.z) * wss[k + 2]
               + tanh_f(qs[k + 3] + kv.w) * wss[k + 3];
        }
        sc[kq][s4] = a;
    }
    __syncthreads();
    if (tid < 64) {
        float v = bsv[0];
#pragma unroll
        for (int q = 0; q < 8; ++q) v += sc[q][tid];
        bool valid = src[ab * SS + tid] != 0;
        float m = valid ? v : -3.0e38f;
        for (int off = 32; off; off >>= 1) m = fmaxf(m, __shfl_xor(m, off));
        float e = valid ? __expf(v - m) : 0.f;
        float ssum = e;
        for (int off = 32; off; off >>= 1) ssum += __shfl_xor(ssum, off);
        float wgt = e / ssum;
        wl[tid] = wgt;
        if (part == 0)
            attn_out[((size_t)ab * TD + t) * SS + tid] = wgt;
    }
    __syncthreads();
    if (tid < 384) {
        // col = gate*1024 + part*128 + jj ; encprojT[(ab*GG + col)*64 + s]
        const int g = tid >> 7, jj = tid & 127;
        const int col = (g << 10) + (part << 7) + jj;
        const float* ep = encprojT + ((size_t)ab * GG + col) * 64;
        float xa = 0.f;
#pragma unroll
        for (int i = 0; i < 16; ++i) {
            f32x4 v = *(const f32x4*)(ep + (i << 2));
            xa += wl[i * 4 + 0] * v.x + wl[i * 4 + 1] * v.y
                + wl[i * 4 + 2] * v.z + wl[i * 4 + 3] * v.w;
        }
        xls[tid] = xa;
    }
    __syncthreads();
    if (tid < 128) {
        const int j = (part << 7) + tid;
        const float* gr = gi + (size_t)(t * BB + ab) * GG;
        float g0 = gr[j] + xls[tid];
        float g1 = gr[HH + j] + xls[128 + tid];
        float g2 = gr[2 * HH + j] + xls[256 + tid];
        float sh0 = hsums[(size_t)0 * BB * HH + (size_t)ab * HH + j];
        float sh1 = hsums[(size_t)1 * BB * HH + (size_t)ab * HH + j];
        float sh2 = hsums[(size_t)2 * BB * HH + (size_t)ab * HH + j];
        float r = sigmoid_f(g0 + sh0 + bhh[j]);
        float z = sigmoid_f(g1 + sh1 + bhh[HH + j]);
        float n = tanh_f(g2 + r * (sh2 + bhh[2 * HH + j]));
        float hold = hbase[(size_t)ab * hstride + j];
        h2all[((size_t)t * BB + ab) * HH + j] = (1.f - z) * n + z * hold;
    }
}

extern "C" void kernel_launch(void* const* d_in, const int* in_sizes, int n_in,
                              void* d_out, int out_size, void* d_ws, size_t ws_size,
                              hipStream_t stream)
{
    const int*   src  = (const int*)d_in[0];
    const int*   tgt  = (const int*)d_in[1];
    const float* eemb = (const float*)d_in[2];
    const float* ewih = (const float*)d_in[3];
    const float* ewhh = (const float*)d_in[4];
    const float* ebih = (const float*)d_in[5];
    const float* ebhh = (const float*)d_in[6];
    const float* wq   = (const float*)d_in[7];
    const float* bq   = (const float*)d_in[8];
    const float* wk   = (const float*)d_in[9];
    const float* bk   = (const float*)d_in[10];
    const float* wsv  = (const float*)d_in[11];
    const float* bsv  = (const float*)d_in[12];
    const float* demb = (const float*)d_in[13];
    const float* dwih = (const float*)d_in[14];
    const float* dwhh = (const float*)d_in[15];
    const float* dbih = (const float*)d_in[16];
    const float* dbhh = (const float*)d_in[17];
    const float* wo   = (const float*)d_in[18];
    const float* bo   = (const float*)d_in[19];
    float* out = (float*)d_out;

    float* w = (float*)d_ws;
    float* enc_gi  = w;                                 // [B*S][3H]; later encprojT
    float* dec_gi  = enc_gi  + (size_t)BB * SS * GG;    // [TD*B][3H]
    float* enc_out = dec_gi  + (size_t)TD * BB * GG;    // [B][S][H]
    float* keys    = enc_out + (size_t)BB * SS * HH;    // [B*S][H]
    float* h2all   = keys    + (size_t)BB * SS * HH;    // [TD][B][H]
    float* qbuf    = h2all   + (size_t)TD * BB * HH;    // [B][H]
    float* hsums   = qbuf    + (size_t)BB * HH;         // [3][B][H]
    int*   didx    = (int*)(hsums + (size_t)3 * BB * HH); // [TD*B]
    unsigned short* Ah = (unsigned short*)(didx + TD * BB + 32); // [MPAD][1024]
    unsigned short* Al = Ah + (size_t)MPAD * 1024;
    unsigned short* Bh = (unsigned short*)w;            // overlay, post-decoder

    float* encprojT = enc_gi;  // overlap: enc_gi dead after encoder finishes
    float* attn_out = out + (size_t)BB * TD * VV;

    k_dec_idx<<<dim3((TD * BB + 255) / 256), 256, 0, stream>>>(tgt, didx);

    k_gemm128<<<dim3(GG / 128, (BB * SS) / 128), 256, 0, stream>>>(
        eemb, ewih, ebih, enc_gi, src, BB * SS, GG, EE, EE, EE, GG, 0);
    k_gemm128<<<dim3(GG / 128, (TD * BB + 127) / 128), 256, 0, stream>>>(
        demb, dwih, dbih, dec_gi, didx, TD * BB, GG, EE, EE, EE + HH, GG, 0);

    for (int s = 0; s < SS; ++s)
        k_enc_step<<<dim3(256), dim3(512), 0, stream>>>(
            enc_gi, ewhh, ebhh, enc_out, s);

    k_gemm128<<<dim3(HH / 128, (BB * SS) / 128), 256, 0, stream>>>(
        enc_out, wk, bk, keys, nullptr, BB * SS, HH, HH, HH, HH, HH, 0);
    // encprojT[b][col][s] = (enc_out @ dec_w_ih[:,E:]^T) transposed
    k_gemm128<<<dim3(GG / 128, (BB * SS) / 128), 256, 0, stream>>>(
        enc_out, dwih + EE, nullptr, encprojT, nullptr,
        BB * SS, GG, HH, HH, EE + HH, GG, 1);

    for (int t = 0; t < TD; ++t) {
        const float* hbase = (t == 0) ? enc_out + (size_t)(SS - 1) * HH
                                      : h2all + (size_t)(t - 1) * BB * HH;
        long hstride = (t == 0) ? (long)SS * HH : (long)HH;
        k_hq<<<dim3(256), dim3(512), 0, stream>>>(
            hbase, hstride, dwhh, wq, bq, qbuf, hsums);
        k_attn_fin<<<dim3(256), dim3(512), 0, stream>>>(
            qbuf, keys, wsv, bsv, src, encprojT, dec_gi, dbhh, hsums,
            hbase, hstride, h2all, attn_out, t);
    }

    // split-bf16 logits: h2all -> Ah/Al; wo -> Bh (overlay); MFMA (m-major).
    k_cvtA<<<dim3(MPAD * 1024 / 1024), 256, 0, stream>>>(h2all, Ah, Al);
    k_cvtB<<<dim3(VV * 1024 / 1024), 256, 0, stream>>>(wo, Bh);
    k_mfma_logits<<<dim3(MPAD / 128, VV / 128), 256, 0, stream>>>(
        Ah, Bh, bo, out);
}

// Round 17
// 3980.822 us; speedup vs baseline: 1.0169x; 1.0169x over previous
//
#include <hip/hip_runtime.h>

// Seq2Seq GRU + Bahdanau attention, fp32. B=32 S=64 T=48 E=512 H=1024 V=32000.
// R17 = R15 restored (measured best: 3986us). R16's transposed-encproj +
// 256-block attn_fin regressed (-62us) and is reverted.
// Final structure: multi-launch recurrence (persistent variants thrash L2 —
// 5 experiments), encproj trick, 64-block attn_fin, split-bf16 MFMA logits
// (single-K-pass, m-major grid).

#define BB 32
#define SS 64
#define TT 48
#define TD 47
#define EE 512
#define HH 1024
#define GG 3072
#define VV 32000
#define SOS_IDX 1
#define MPAD 1536          // 1504 rows padded to 12*128

typedef float f32x4 __attribute__((ext_vector_type(4)));
typedef short bf16x8 __attribute__((ext_vector_type(8)));

static __device__ __forceinline__ float sigmoid_f(float x) {
    return 1.0f / (1.0f + __expf(-x));
}
static __device__ __forceinline__ float tanh_f(float x) {
    return 1.0f - 2.0f / (__expf(2.0f * x) + 1.0f);
}
static __device__ __forceinline__ unsigned short f2bf(float f) {
    unsigned u = __float_as_uint(f);
    u = u + 0x7fffu + ((u >> 16) & 1u);
    return (unsigned short)(u >> 16);
}

__global__ void k_dec_idx(const int* __restrict__ tgt, int* __restrict__ idx) {
    int m = blockIdx.x * 256 + threadIdx.x;
    if (m < TD * BB) {
        int t = m >> 5, b = m & 31;
        idx[m] = (t == 0) ? SOS_IDX : tgt[b * TT + t];
    }
}

// ---------------- fp32 128x128 GEMM (non-logits projections) ----------------
__global__ __launch_bounds__(256) void k_gemm128(
    const float* __restrict__ A, const float* __restrict__ Wt,
    const float* __restrict__ bias, float* __restrict__ C,
    const int* __restrict__ rowidx,
    int M, int N, int K, int lda, int ldw, int ldc)
{
    __shared__ __align__(16) float As[16][128];
    __shared__ __align__(16) float Bs[16][128];
    const int tid = threadIdx.x;
    const int tm = tid >> 4, tn = tid & 15;
    const int row0 = blockIdx.y * 128;
    const int col0 = blockIdx.x * 128;
    const int lr = tid >> 1;
    const int lq = tid & 1;

    long arow_off = -1;
    {
        int arow = row0 + lr;
        if (arow < M) {
            int r = rowidx ? rowidx[arow] : arow;
            arow_off = (long)r * lda;
        }
    }
    const long wrow_off = (long)(col0 + lr) * ldw;

    float acc[8][8];
#pragma unroll
    for (int i = 0; i < 8; ++i)
#pragma unroll
        for (int j = 0; j < 8; ++j) acc[i][j] = 0.f;

    for (int k0 = 0; k0 < K; k0 += 16) {
        f32x4 av0 = {0.f,0.f,0.f,0.f}, av1 = {0.f,0.f,0.f,0.f};
        if (arow_off >= 0) {
            av0 = *(const f32x4*)(A + arow_off + k0 + lq * 8);
            av1 = *(const f32x4*)(A + arow_off + k0 + lq * 8 + 4);
        }
        f32x4 wv0 = *(const f32x4*)(Wt + wrow_off + k0 + lq * 8);
        f32x4 wv1 = *(const f32x4*)(Wt + wrow_off + k0 + lq * 8 + 4);
        __syncthreads();
#pragma unroll
        for (int i = 0; i < 4; ++i) {
            As[lq * 8 + i][lr] = av0[i];
            As[lq * 8 + 4 + i][lr] = av1[i];
            Bs[lq * 8 + i][lr] = wv0[i];
            Bs[lq * 8 + 4 + i][lr] = wv1[i];
        }
        __syncthreads();
#pragma unroll
        for (int kk = 0; kk < 16; ++kk) {
            f32x4 a0 = *(const f32x4*)&As[kk][tm * 4];
            f32x4 a1 = *(const f32x4*)&As[kk][64 + tm * 4];
            f32x4 b0 = *(const f32x4*)&Bs[kk][tn * 4];
            f32x4 b1 = *(const f32x4*)&Bs[kk][64 + tn * 4];
            float a[8], b[8];
#pragma unroll
            for (int i = 0; i < 4; ++i) {
                a[i] = a0[i]; a[4 + i] = a1[i];
                b[i] = b0[i]; b[4 + i] = b1[i];
            }
#pragma unroll
            for (int i = 0; i < 8; ++i)
#pragma unroll
                for (int j = 0; j < 8; ++j) acc[i][j] += a[i] * b[j];
        }
    }

    f32x4 bv0 = {0.f,0.f,0.f,0.f}, bv1 = {0.f,0.f,0.f,0.f};
    if (bias) {
        bv0 = *(const f32x4*)(bias + col0 + tn * 4);
        bv1 = *(const f32x4*)(bias + col0 + 64 + tn * 4);
    }
#pragma unroll
    for (int i = 0; i < 8; ++i) {
        int m = row0 + ((i < 4) ? (tm * 4 + i) : (64 + tm * 4 + i - 4));
        if (m >= M) continue;
        f32x4 v0, v1;
#pragma unroll
        for (int j = 0; j < 4; ++j) {
            v0[j] = acc[i][j] + bv0[j];
            v1[j] = acc[i][4 + j] + bv1[j];
        }
        *(f32x4*)(C + (long)m * ldc + col0 + tn * 4) = v0;
        *(f32x4*)(C + (long)m * ldc + col0 + 64 + tn * 4) = v1;
    }
}

// ---------------- conversions for split-bf16 logits ----------------
__global__ __launch_bounds__(256) void k_cvtA(
    const float* __restrict__ A, unsigned short* __restrict__ Ah,
    unsigned short* __restrict__ Al)
{
    size_t i4 = ((size_t)blockIdx.x * 256 + threadIdx.x) * 4;
    int row = (int)(i4 >> 10);
    f32x4 v = {0.f, 0.f, 0.f, 0.f};
    if (row < TD * BB) v = *(const f32x4*)(A + i4);
    ushort4 h, l;
    float hf;
    h.x = f2bf(v.x); hf = __uint_as_float((unsigned)h.x << 16); l.x = f2bf(v.x - hf);
    h.y = f2bf(v.y); hf = __uint_as_float((unsigned)h.y << 16); l.y = f2bf(v.y - hf);
    h.z = f2bf(v.z); hf = __uint_as_float((unsigned)h.z << 16); l.z = f2bf(v.z - hf);
    h.w = f2bf(v.w); hf = __uint_as_float((unsigned)h.w << 16); l.w = f2bf(v.w - hf);
    *(ushort4*)(Ah + i4) = h;
    *(ushort4*)(Al + i4) = l;
}

__global__ __launch_bounds__(256) void k_cvtB(
    const float* __restrict__ Bsrc, unsigned short* __restrict__ Bh)
{
    size_t i4 = ((size_t)blockIdx.x * 256 + threadIdx.x) * 4;
    f32x4 v = *(const f32x4*)(Bsrc + i4);
    ushort4 h;
    h.x = f2bf(v.x); h.y = f2bf(v.y); h.z = f2bf(v.z); h.w = f2bf(v.w);
    *(ushort4*)(Bh + i4) = h;
}

// ---------------- split-bf16 MFMA logits GEMM ----------------
// C[orow(m)][n] = sum_k (Ah+Al)[m][k] * Bh[n][k] + bo[n].
// Single K=1024 loop; per kt the Bh tile is loaded ONCE and used for both
// Ah and Al MFMA sets. 128x128 tile, 4 waves, 16x16x32 bf16 MFMA,
// XOR-swizzled LDS, m-major grid.
__global__ __launch_bounds__(256) void k_mfma_logits(
    const unsigned short* __restrict__ Ah,   // [MPAD][1024]; Al at +MPAD*1024
    const unsigned short* __restrict__ Bh,   // [VV][1024]
    const float* __restrict__ bo, float* __restrict__ C)
{
    __shared__ __align__(16) unsigned short As0[128 * 64];
    __shared__ __align__(16) unsigned short As1[128 * 64];
    __shared__ __align__(16) unsigned short Bs[128 * 64];
    const int tid = threadIdx.x;
    const int m0 = blockIdx.x * 128;     // m-major grid
    const int n0 = blockIdx.y * 128;
    const int r = tid >> 1, half = tid & 1;
    const int lane = tid & 63, wid = tid >> 6;
    const int wm = wid >> 1, wn = wid & 1;

    f32x4 acc[4][4];
#pragma unroll
    for (int i = 0; i < 4; ++i)
#pragma unroll
        for (int j = 0; j < 4; ++j) acc[i][j] = (f32x4){0.f, 0.f, 0.f, 0.f};

    char* As0B = (char*)As0;
    char* As1B = (char*)As1;
    char* BsB  = (char*)Bs;
    const int lwb = r * 128 + half * 64;
    const int swz = (r & 7) << 4;

    for (int kt = 0; kt < 16; ++kt) {
        const int kb = kt * 64;
        const unsigned short* Ap0 = Ah + (size_t)(m0 + r) * 1024 + kb + half * 32;
        const unsigned short* Ap1 = Ap0 + (size_t)MPAD * 1024;
        const unsigned short* Bp  = Bh + (size_t)(n0 + r) * 1024 + kb + half * 32;
        f32x4 a0 = *(const f32x4*)(Ap0 + 0);
        f32x4 a1 = *(const f32x4*)(Ap0 + 8);
        f32x4 a2 = *(const f32x4*)(Ap0 + 16);
        f32x4 a3 = *(const f32x4*)(Ap0 + 24);
        f32x4 c0 = *(const f32x4*)(Ap1 + 0);
        f32x4 c1 = *(const f32x4*)(Ap1 + 8);
        f32x4 c2 = *(const f32x4*)(Ap1 + 16);
        f32x4 c3 = *(const f32x4*)(Ap1 + 24);
        f32x4 b0 = *(const f32x4*)(Bp + 0);
        f32x4 b1 = *(const f32x4*)(Bp + 8);
        f32x4 b2 = *(const f32x4*)(Bp + 16);
        f32x4 b3 = *(const f32x4*)(Bp + 24);
        __syncthreads();
        *(f32x4*)(As0B + ((lwb + 0)  ^ swz)) = a0;
        *(f32x4*)(As0B + ((lwb + 16) ^ swz)) = a1;
        *(f32x4*)(As0B + ((lwb + 32) ^ swz)) = a2;
        *(f32x4*)(As0B + ((lwb + 48) ^ swz)) = a3;
        *(f32x4*)(As1B + ((lwb + 0)  ^ swz)) = c0;
        *(f32x4*)(As1B + ((lwb + 16) ^ swz)) = c1;
        *(f32x4*)(As1B + ((lwb + 32) ^ swz)) = c2;
        *(f32x4*)(As1B + ((lwb + 48) ^ swz)) = c3;
        *(f32x4*)(BsB  + ((lwb + 0)  ^ swz)) = b0;
        *(f32x4*)(BsB  + ((lwb + 16) ^ swz)) = b1;
        *(f32x4*)(BsB  + ((lwb + 32) ^ swz)) = b2;
        *(f32x4*)(BsB  + ((lwb + 48) ^ swz)) = b3;
        __syncthreads();
#pragma unroll
        for (int ks = 0; ks < 2; ++ks) {
            bf16x8 bf[4], af[4], ag[4];
#pragma unroll
            for (int u = 0; u < 4; ++u) {
                int nl = wn * 64 + u * 16 + (lane & 15);
                int byteB = nl * 128 + ks * 64 + ((lane >> 4) << 4);
                bf[u] = *(const bf16x8*)(BsB + (byteB ^ ((nl & 7) << 4)));
                int ml = wm * 64 + u * 16 + (lane & 15);
                int byteA = ml * 128 + ks * 64 + ((lane >> 4) << 4);
                af[u] = *(const bf16x8*)(As0B + (byteA ^ ((ml & 7) << 4)));
                ag[u] = *(const bf16x8*)(As1B + (byteA ^ ((ml & 7) << 4)));
            }
#pragma unroll
            for (int mi = 0; mi < 4; ++mi)
#pragma unroll
                for (int ni = 0; ni < 4; ++ni) {
                    acc[mi][ni] = __builtin_amdgcn_mfma_f32_16x16x32_bf16(
                        af[mi], bf[ni], acc[mi][ni], 0, 0, 0);
                    acc[mi][ni] = __builtin_amdgcn_mfma_f32_16x16x32_bf16(
                        ag[mi], bf[ni], acc[mi][ni], 0, 0, 0);
                }
        }
    }

    const int cl = lane & 15, rq = lane >> 4;
#pragma unroll
    for (int ni = 0; ni < 4; ++ni) {
        int col = n0 + wn * 64 + ni * 16 + cl;
        float bias = bo[col];
#pragma unroll
        for (int mi = 0; mi < 4; ++mi) {
#pragma unroll
            for (int j = 0; j < 4; ++j) {
                int m = m0 + wm * 64 + mi * 16 + rq * 4 + j;
                if (m < TD * BB) {
                    int orow = (m & 31) * TD + (m >> 5);
                    C[(size_t)orow * VV + col] = acc[mi][ni][j] + bias;
                }
            }
        }
    }
}

// ---------------- encoder step ----------------
__global__ __launch_bounds__(512, 2) void k_enc_step(
    const float* __restrict__ gi, const float* __restrict__ Whh,
    const float* __restrict__ bhh, float* __restrict__ enc_out, int s)
{
    __shared__ float red[12][16][32];
    __shared__ float sums[12][32];
    const int tid = threadIdx.x, bid = blockIdx.x;
    const int b = tid & 31, ks = tid >> 5;
    const int j0 = bid * 4;
    const int kc = ks * 64;

    float acc[12];
#pragma unroll
    for (int u = 0; u < 12; ++u) acc[u] = 0.f;
    if (s > 0) {
        f32x4 hreg[16];
        const float* hb = enc_out + ((size_t)b * SS + (s - 1)) * HH + kc;
#pragma unroll
        for (int i = 0; i < 16; ++i) hreg[i] = *(const f32x4*)(hb + (i << 2));
#pragma unroll
        for (int jj = 0; jj < 4; ++jj) {
            const float* pr = Whh + ((size_t)(j0 + jj) << 10) + kc;
            const float* pz = Whh + ((size_t)(HH + j0 + jj) << 10) + kc;
            const float* pn = Whh + ((size_t)(2 * HH + j0 + jj) << 10) + kc;
            float ar = 0.f, az = 0.f, an = 0.f;
#pragma unroll
            for (int i = 0; i < 16; ++i) {
                f32x4 h4 = hreg[i];
                f32x4 w;
                w = *(const f32x4*)(pr + (i << 2));
                ar += h4.x * w.x + h4.y * w.y + h4.z * w.z + h4.w * w.w;
                w = *(const f32x4*)(pz + (i << 2));
                az += h4.x * w.x + h4.y * w.y + h4.z * w.z + h4.w * w.w;
                w = *(const f32x4*)(pn + (i << 2));
                an += h4.x * w.x + h4.y * w.y + h4.z * w.z + h4.w * w.w;
            }
            acc[jj] = ar; acc[4 + jj] = az; acc[8 + jj] = an;
        }
    }
#pragma unroll
    for (int u = 0; u < 12; ++u) red[u][ks][b] = acc[u];
    __syncthreads();
    if (tid < 384) {
        int u = tid >> 5, fb = tid & 31;
        float x = 0.f;
#pragma unroll
        for (int q = 0; q < 16; ++q) x += red[u][q][fb];
        sums[u][fb] = x;
    }
    __syncthreads();
    if (tid < 32) {
        const f32x4 bh0 = *(const f32x4*)(bhh + j0);
        const f32x4 bh1 = *(const f32x4*)(bhh + HH + j0);
        const f32x4 bh2 = *(const f32x4*)(bhh + 2 * HH + j0);
        const float* gr = gi + (size_t)(tid * SS + s) * GG;
        f32x4 g0 = *(const f32x4*)(gr + j0);
        f32x4 g1 = *(const f32x4*)(gr + HH + j0);
        f32x4 g2 = *(const f32x4*)(gr + 2 * HH + j0);
        f32x4 hold = {0.f, 0.f, 0.f, 0.f};
        if (s > 0) hold = *(const f32x4*)(enc_out + ((size_t)tid * SS + (s - 1)) * HH + j0);
        f32x4 hn;
#pragma unroll
        for (int e = 0; e < 4; ++e) {
            float r = sigmoid_f(g0[e] + sums[e][tid] + bh0[e]);
            float z = sigmoid_f(g1[e] + sums[4 + e][tid] + bh1[e]);
            float n = tanh_f(g2[e] + r * (sums[8 + e][tid] + bh2[e]));
            hn[e] = (1.f - z) * n + z * hold[e];
        }
        *(f32x4*)(enc_out + ((size_t)tid * SS + s) * HH + j0) = hn;
    }
}

// ---------------- decoder K1: h-side dots + q ----------------
__global__ __launch_bounds__(512, 2) void k_hq(
    const float* __restrict__ hbase, long hstride,
    const float* __restrict__ Whh, const float* __restrict__ wq,
    const float* __restrict__ bq, float* __restrict__ qbuf,
    float* __restrict__ hsums)
{
    __shared__ float red[16][16][32];
    __shared__ float qsum[4][32];
    const int tid = threadIdx.x, bid = blockIdx.x;
    const int b = tid & 31, ks = tid >> 5;
    const int j0 = bid * 4;
    const int kc = ks * 64;

    f32x4 hreg[16];
    const float* hb = hbase + (size_t)b * hstride + kc;
#pragma unroll
    for (int i = 0; i < 16; ++i) hreg[i] = *(const f32x4*)(hb + (i << 2));
    float acc[16];
#pragma unroll
    for (int jj = 0; jj < 4; ++jj) {
        const float* pr = Whh + ((size_t)(j0 + jj) << 10) + kc;
        const float* pz = Whh + ((size_t)(HH + j0 + jj) << 10) + kc;
        const float* pn = Whh + ((size_t)(2 * HH + j0 + jj) << 10) + kc;
        const float* pq = wq + ((size_t)(j0 + jj) << 10) + kc;
        float ar = 0.f, az = 0.f, an = 0.f, aq = 0.f;
#pragma unroll
        for (int i = 0; i < 16; ++i) {
            f32x4 h4 = hreg[i];
            f32x4 w;
            w = *(const f32x4*)(pr + (i << 2));
            ar += h4.x * w.x + h4.y * w.y + h4.z * w.z + h4.w * w.w;
            w = *(const f32x4*)(pz + (i << 2));
            az += h4.x * w.x + h4.y * w.y + h4.z * w.z + h4.w * w.w;
            w = *(const f32x4*)(pn + (i << 2));
            an += h4.x * w.x + h4.y * w.y + h4.z * w.z + h4.w * w.w;
            w = *(const f32x4*)(pq + (i << 2));
            aq += h4.x * w.x + h4.y * w.y + h4.z * w.z + h4.w * w.w;
        }
        acc[jj] = ar; acc[4 + jj] = az; acc[8 + jj] = an; acc[12 + jj] = aq;
    }
#pragma unroll
    for (int u = 0; u < 16; ++u) red[u][ks][b] = acc[u];
    __syncthreads();
    {
        int u = tid >> 5, fb = tid & 31;
        float x = 0.f;
#pragma unroll
        for (int q = 0; q < 16; ++q) x += red[u][q][fb];
        if (u < 12) {
            int g = u >> 2, jj = u & 3;
            hsums[(size_t)g * BB * HH + (size_t)fb * HH + j0 + jj] = x;
        } else {
            qsum[u - 12][fb] = x;
        }
    }
    __syncthreads();
    if (tid < 32) {
        const f32x4 bq4 = *(const f32x4*)(bq + j0);
        f32x4 qv;
        qv.x = qsum[0][tid] + bq4.x;
        qv.y = qsum[1][tid] + bq4.y;
        qv.z = qsum[2][tid] + bq4.z;
        qv.w = qsum[3][tid] + bq4.w;
        *(f32x4*)(qbuf + (size_t)tid * HH + j0) = qv;
    }
}

// ---------------- decoder K2: attention + xsum + finalize ----------------
// 64 blocks: ab = bid&31, part = bid>>5. Both parts compute scores+softmax
// (redundant); each part does xsum + finalize for j in [part*512, +512).
__global__ __launch_bounds__(512, 2) void k_attn_fin(
    const float* __restrict__ qbuf, const float* __restrict__ keys,
    const float* __restrict__ wsv, const float* __restrict__ bsv,
    const int* __restrict__ src, const float* __restrict__ encproj,
    const float* __restrict__ gi, const float* __restrict__ bhh,
    const float* __restrict__ hsums, const float* __restrict__ hbase,
    long hstride, float* __restrict__ h2all, float* __restrict__ attn_out,
    int t)
{
    __shared__ float qs[HH];
    __shared__ float wss[HH];
    __shared__ float sc[8][64];
    __shared__ float wl[64];
    __shared__ float xls[3 * 512];
    const int ab = blockIdx.x & 31, part = blockIdx.x >> 5;
    const int tid = threadIdx.x;
    if (tid < 256) {
        *(f32x4*)&qs[tid * 4] = *(const f32x4*)(qbuf + (size_t)ab * HH + tid * 4);
        *(f32x4*)&wss[tid * 4] = *(const f32x4*)(wsv + tid * 4);
    }
    __syncthreads();
    {
        const int s4 = tid >> 3, kq = tid & 7;
        const float* kr = keys + (size_t)(ab * SS + s4) * HH + kq * 128;
        float a = 0.f;
        for (int i = 0; i < 32; ++i) {
            f32x4 kv = *(const f32x4*)(kr + (i << 2));
            int k = kq * 128 + (i << 2);
            a += tanh_f(qs[k] + kv.x) * wss[k]
               + tanh_f(qs[k + 1] + kv.y) * wss[k + 1]
               + tanh_f(qs[k + 2] + kv.z) * wss[k + 2]
               + tanh_f(qs[k + 3] + kv.w) * wss[k + 3];
        }
        sc[kq][s4] = a;
    }
    __syncthreads();
    if (tid < 64) {
        float v = bsv[0];
#pragma unroll
        for (int q = 0; q < 8; ++q) v += sc[q][tid];
        bool valid = src[ab * SS + tid] != 0;
        float m = valid ? v : -3.0e38f;
        for (int off = 32; off; off >>= 1) m = fmaxf(m, __shfl_xor(m, off));
        float e = valid ? __expf(v - m) : 0.f;
        float ssum = e;
        for (int off = 32; off; off >>= 1) ssum += __shfl_xor(ssum, off);
        float wgt = e / ssum;
        wl[tid] = wgt;
        if (part == 0)
            attn_out[((size_t)ab * TD + t) * SS + tid] = wgt;
    }
    __syncthreads();
    {
        float xa[3] = {0.f, 0.f, 0.f};
        const int colbase = part * 512 + tid;
        for (int s2 = 0; s2 < SS; ++s2) {
            float wgt = wl[s2];
            const float* ep = encproj + (size_t)(ab * SS + s2) * GG + colbase;
#pragma unroll
            for (int u = 0; u < 3; ++u)
                xa[u] += wgt * ep[u * HH];
        }
#pragma unroll
        for (int u = 0; u < 3; ++u) xls[u * 512 + tid] = xa[u];
    }
    __syncthreads();
    {
        const int j = part * 512 + tid;
        const float* gr = gi + (size_t)(t * BB + ab) * GG;
        float g0 = gr[j] + xls[tid];
        float g1 = gr[HH + j] + xls[512 + tid];
        float g2 = gr[2 * HH + j] + xls[1024 + tid];
        float sh0 = hsums[(size_t)0 * BB * HH + (size_t)ab * HH + j];
        float sh1 = hsums[(size_t)1 * BB * HH + (size_t)ab * HH + j];
        float sh2 = hsums[(size_t)2 * BB * HH + (size_t)ab * HH + j];
        float r = sigmoid_f(g0 + sh0 + bhh[j]);
        float z = sigmoid_f(g1 + sh1 + bhh[HH + j]);
        float n = tanh_f(g2 + r * (sh2 + bhh[2 * HH + j]));
        float hold = hbase[(size_t)ab * hstride + j];
        h2all[((size_t)t * BB + ab) * HH + j] = (1.f - z) * n + z * hold;
    }
}

extern "C" void kernel_launch(void* const* d_in, const int* in_sizes, int n_in,
                              void* d_out, int out_size, void* d_ws, size_t ws_size,
                              hipStream_t stream)
{
    const int*   src  = (const int*)d_in[0];
    const int*   tgt  = (const int*)d_in[1];
    const float* eemb = (const float*)d_in[2];
    const float* ewih = (const float*)d_in[3];
    const float* ewhh = (const float*)d_in[4];
    const float* ebih = (const float*)d_in[5];
    const float* ebhh = (const float*)d_in[6];
    const float* wq   = (const float*)d_in[7];
    const float* bq   = (const float*)d_in[8];
    const float* wk   = (const float*)d_in[9];
    const float* bk   = (const float*)d_in[10];
    const float* wsv  = (const float*)d_in[11];
    const float* bsv  = (const float*)d_in[12];
    const float* demb = (const float*)d_in[13];
    const float* dwih = (const float*)d_in[14];
    const float* dwhh = (const float*)d_in[15];
    const float* dbih = (const float*)d_in[16];
    const float* dbhh = (const float*)d_in[17];
    const float* wo   = (const float*)d_in[18];
    const float* bo   = (const float*)d_in[19];
    float* out = (float*)d_out;

    float* w = (float*)d_ws;
    float* enc_gi  = w;                                 // [B*S][3H]; later encproj
    float* dec_gi  = enc_gi  + (size_t)BB * SS * GG;    // [TD*B][3H]
    float* enc_out = dec_gi  + (size_t)TD * BB * GG;    // [B][S][H]
    float* keys    = enc_out + (size_t)BB * SS * HH;    // [B*S][H]
    float* h2all   = keys    + (size_t)BB * SS * HH;    // [TD][B][H]
    float* qbuf    = h2all   + (size_t)TD * BB * HH;    // [B][H]
    float* hsums   = qbuf    + (size_t)BB * HH;         // [3][B][H]
    int*   didx    = (int*)(hsums + (size_t)3 * BB * HH); // [TD*B]
    unsigned short* Ah = (unsigned short*)(didx + TD * BB + 32); // [MPAD][1024]
    unsigned short* Al = Ah + (size_t)MPAD * 1024;
    unsigned short* Bh = (unsigned short*)w;            // overlay, post-decoder

    float* encproj = enc_gi;   // overlap: enc_gi dead after encoder finishes
    float* attn_out = out + (size_t)BB * TD * VV;

    k_dec_idx<<<dim3((TD * BB + 255) / 256), 256, 0, stream>>>(tgt, didx);

    k_gemm128<<<dim3(GG / 128, (BB * SS) / 128), 256, 0, stream>>>(
        eemb, ewih, ebih, enc_gi, src, BB * SS, GG, EE, EE, EE, GG);
    k_gemm128<<<dim3(GG / 128, (TD * BB + 127) / 128), 256, 0, stream>>>(
        demb, dwih, dbih, dec_gi, didx, TD * BB, GG, EE, EE, EE + HH, GG);

    for (int s = 0; s < SS; ++s)
        k_enc_step<<<dim3(256), dim3(512), 0, stream>>>(
            enc_gi, ewhh, ebhh, enc_out, s);

    k_gemm128<<<dim3(HH / 128, (BB * SS) / 128), 256, 0, stream>>>(
        enc_out, wk, bk, keys, nullptr, BB * SS, HH, HH, HH, HH, HH);
    k_gemm128<<<dim3(GG / 128, (BB * SS) / 128), 256, 0, stream>>>(
        enc_out, dwih + EE, nullptr, encproj, nullptr,
        BB * SS, GG, HH, HH, EE + HH, GG);

    for (int t = 0; t < TD; ++t) {
        const float* hbase = (t == 0) ? enc_out + (size_t)(SS - 1) * HH
                                      : h2all + (size_t)(t - 1) * BB * HH;
        long hstride = (t == 0) ? (long)SS * HH : (long)HH;
        k_hq<<<dim3(256), dim3(512), 0, stream>>>(
            hbase, hstride, dwhh, wq, bq, qbuf, hsums);
        k_attn_fin<<<dim3(64), dim3(512), 0, stream>>>(
            qbuf, keys, wsv, bsv, src, encproj, dec_gi, dbhh, hsums,
            hbase, hstride, h2all, attn_out, t);
    }

    // split-bf16 logits: h2all -> Ah/Al; wo -> Bh (overlay); MFMA (m-major).
    k_cvtA<<<dim3(MPAD * 1024 / 1024), 256, 0, stream>>>(h2all, Ah, Al);
    k_cvtB<<<dim3(VV * 1024 / 1024), 256, 0, stream>>>(wo, Bh);
    k_mfma_logits<<<dim3(MPAD / 128, VV / 128), 256, 0, stream>>>(
        Ah, Bh, bo, out);
}